// Round 2
// baseline (153.619 us; speedup 1.0000x reference)
//
#include <hip/hip_runtime.h>
#include <math.h>

#define NR 8
#define NB 8
#define NH 32
#define NKVH 8
#define NG 4
#define ND 128
#define NDV 128
#define NPAGE 2048
#define CCHUNK 256
#define NSP 8                 // max chunks per (r,b): ceil(2048/256)
#define NPART (NR*NSP)        // 64 partials per (b,kvh,g)
#define KSTR (NKVH*ND)        // 1024 floats per page
#define PSTRIDE (NB*NKVH*NG)  // 2048 rows per partial slot
#define QSCALE 0.088388347648318447f  /* 1/sqrt(128) */

__device__ __forceinline__ float half_reduce(float v) {
  // xor masks <= 16 stay inside each 32-lane half of the wave64
  v += __shfl_xor(v, 16);
  v += __shfl_xor(v, 8);
  v += __shfl_xor(v, 4);
  v += __shfl_xor(v, 2);
  v += __shfl_xor(v, 1);
  return v;
}

__global__ __launch_bounds__(256, 4) void attn_partial(
    const float* __restrict__ q,
    const float* __restrict__ k_cache,
    const float* __restrict__ v_cache,
    const int* __restrict__ kv_lens,
    const int* __restrict__ block_table,
    float* __restrict__ ws_out,   // [NPART][NB][NKVH][NG][NDV]
    float* __restrict__ ws_lse)   // [NPART][NB][NKVH][NG]
{
  const int bid = blockIdx.x;
  const int sp  = bid & (NSP - 1);
  const int kvh = (bid >> 3) & (NKVH - 1);
  const int b   = (bid >> 6) & (NB - 1);
  const int r   = bid >> 9;

  const int tid = threadIdx.x;
  const int gid = tid >> 5;   // 8 half-wave groups
  const int sub = tid & 31;   // lane in group; owns dims 4*sub..4*sub+3

  const int len = kv_lens[r * NB + b];
  const int lo  = sp * CCHUNK;
  const int pi  = r * NSP + sp;
  const size_t pbase = (((size_t)pi * NB + b) * NKVH + kvh) * NG;

  if (lo >= len) {               // empty chunk: sentinel lse, no output needed
    if (tid < NG) ws_lse[pbase + tid] = -1e30f;
    return;
  }
  const int hi = min(len, lo + CCHUNK);

  const int* bt = block_table + (r * NB + b) * NPAGE;
  const float* Kr = k_cache + (size_t)r * NPAGE * KSTR + kvh * ND  + 4 * sub;
  const float* Vr = v_cache + (size_t)r * NPAGE * KSTR + kvh * NDV + 4 * sub;

  const float* qb = q + (b * NH + kvh * NG) * ND + 4 * sub;
  float4 qh[NG];
#pragma unroll
  for (int h = 0; h < NG; ++h) {
    qh[h] = *(const float4*)(qb + h * ND);
    qh[h].x *= QSCALE; qh[h].y *= QSCALE; qh[h].z *= QSCALE; qh[h].w *= QSCALE;
  }

  float m[NG], l[NG];
  float4 acc[NG];
#pragma unroll
  for (int h = 0; h < NG; ++h) {
    m[h] = -INFINITY; l[h] = 0.f;
    acc[h].x = 0.f; acc[h].y = 0.f; acc[h].z = 0.f; acc[h].w = 0.f;
  }

  // group gid owns contiguous tokens [g0, g0+32) of this chunk
  const int g0 = lo + (gid << 5);
  int nval = hi - g0;
  nval = nval < 0 ? 0 : (nval > 32 ? 32 : nval);
  int mypage = 0;
  if (sub < nval) mypage = bt[g0 + sub];   // coalesced page-id preload

  int j = 0;
  for (; j + 4 <= nval; j += 4) {
    const int p0 = __shfl(mypage, j + 0, 32);
    const int p1 = __shfl(mypage, j + 1, 32);
    const int p2 = __shfl(mypage, j + 2, 32);
    const int p3 = __shfl(mypage, j + 3, 32);
    const float4 k0 = *(const float4*)(Kr + (size_t)p0 * KSTR);
    const float4 k1 = *(const float4*)(Kr + (size_t)p1 * KSTR);
    const float4 k2 = *(const float4*)(Kr + (size_t)p2 * KSTR);
    const float4 k3 = *(const float4*)(Kr + (size_t)p3 * KSTR);
    const float4 w0 = *(const float4*)(Vr + (size_t)p0 * KSTR);
    const float4 w1 = *(const float4*)(Vr + (size_t)p1 * KSTR);
    const float4 w2 = *(const float4*)(Vr + (size_t)p2 * KSTR);
    const float4 w3 = *(const float4*)(Vr + (size_t)p3 * KSTR);

    float s[NG][4];
#pragma unroll
    for (int h = 0; h < NG; ++h) {
      s[h][0] = k0.x * qh[h].x + k0.y * qh[h].y + k0.z * qh[h].z + k0.w * qh[h].w;
      s[h][1] = k1.x * qh[h].x + k1.y * qh[h].y + k1.z * qh[h].z + k1.w * qh[h].w;
      s[h][2] = k2.x * qh[h].x + k2.y * qh[h].y + k2.z * qh[h].z + k2.w * qh[h].w;
      s[h][3] = k3.x * qh[h].x + k3.y * qh[h].y + k3.z * qh[h].z + k3.w * qh[h].w;
    }
#pragma unroll
    for (int h = 0; h < NG; ++h) {
#pragma unroll
      for (int t = 0; t < 4; ++t) s[h][t] = half_reduce(s[h][t]);
    }
#pragma unroll
    for (int h = 0; h < NG; ++h) {
      const float mx = fmaxf(fmaxf(s[h][0], s[h][1]), fmaxf(s[h][2], s[h][3]));
      if (mx > m[h]) {            // rare rescale (uniform within group)
        const float sc = __expf(m[h] - mx);
        m[h] = mx;
        l[h] *= sc;
        acc[h].x *= sc; acc[h].y *= sc; acc[h].z *= sc; acc[h].w *= sc;
      }
      const float e0 = __expf(s[h][0] - m[h]);
      const float e1 = __expf(s[h][1] - m[h]);
      const float e2 = __expf(s[h][2] - m[h]);
      const float e3 = __expf(s[h][3] - m[h]);
      l[h] += (e0 + e1) + (e2 + e3);
      acc[h].x += e0 * w0.x + e1 * w1.x + e2 * w2.x + e3 * w3.x;
      acc[h].y += e0 * w0.y + e1 * w1.y + e2 * w2.y + e3 * w3.y;
      acc[h].z += e0 * w0.z + e1 * w1.z + e2 * w2.z + e3 * w3.z;
      acc[h].w += e0 * w0.w + e1 * w1.w + e2 * w2.w + e3 * w3.w;
    }
  }
  for (; j < nval; ++j) {   // tail 0..3 tokens
    const int p0 = __shfl(mypage, j, 32);
    const float4 k0 = *(const float4*)(Kr + (size_t)p0 * KSTR);
    const float4 w0 = *(const float4*)(Vr + (size_t)p0 * KSTR);
#pragma unroll
    for (int h = 0; h < NG; ++h) {
      float st = k0.x * qh[h].x + k0.y * qh[h].y + k0.z * qh[h].z + k0.w * qh[h].w;
      st = half_reduce(st);
      if (st > m[h]) {
        const float sc = __expf(m[h] - st);
        m[h] = st;
        l[h] = l[h] * sc + 1.0f;
        acc[h].x = acc[h].x * sc + w0.x;
        acc[h].y = acc[h].y * sc + w0.y;
        acc[h].z = acc[h].z * sc + w0.z;
        acc[h].w = acc[h].w * sc + w0.w;
      } else {
        const float e = __expf(st - m[h]);
        l[h] += e;
        acc[h].x += e * w0.x; acc[h].y += e * w0.y;
        acc[h].z += e * w0.z; acc[h].w += e * w0.w;
      }
    }
  }

  // ---- merge the 8 groups via LDS ----
  __shared__ float lds_m[8][NG];
  __shared__ float lds_l[8][NG];
  __shared__ float lds_a[8][NG][NDV];
  if (sub == 0) {
#pragma unroll
    for (int h = 0; h < NG; ++h) { lds_m[gid][h] = m[h]; lds_l[gid][h] = l[h]; }
  }
#pragma unroll
  for (int h = 0; h < NG; ++h) {
    float* p = &lds_a[gid][h][4 * sub];
    p[0] = acc[h].x; p[1] = acc[h].y; p[2] = acc[h].z; p[3] = acc[h].w;
  }
  __syncthreads();

  __shared__ float Mg[NG], Lg[NG];
  if (tid < NG) {
    float M = -INFINITY;
    for (int p = 0; p < 8; ++p) M = fmaxf(M, lds_m[p][tid]);
    float L = 0.f;
    for (int p = 0; p < 8; ++p) {
      const float mm = lds_m[p][tid];
      if (mm > -INFINITY) L += lds_l[p][tid] * __expf(mm - M);
    }
    Mg[tid] = M; Lg[tid] = L;
  }
  __syncthreads();

  for (int idx = tid; idx < NG * NDV; idx += 256) {
    const int g = idx >> 7;
    const int d = idx & (NDV - 1);
    const float M = Mg[g];
    const float L = Lg[g];
    float a = 0.f;
    for (int p = 0; p < 8; ++p) {
      const float mm = lds_m[p][g];
      if (mm > -INFINITY) a += lds_a[p][g][d] * __expf(mm - M);
    }
    ws_out[(pbase + g) * NDV + d] = (L > 0.f) ? (a / L) : 0.f;
    if (d == 0) ws_lse[pbase + g] = (L > 0.f) ? (M + __logf(L)) : -1e30f;
  }
}

// One block per (b,kvh,g); logsumexp-weighted combine over NPART partials.
__global__ __launch_bounds__(128) void attn_combine(
    const float* __restrict__ ws_out,
    const float* __restrict__ ws_lse,
    float* __restrict__ out)
{
  const int bkg = blockIdx.x;      // (b*NKVH + kvh)*NG + g  == output row
  const int d   = threadIdx.x;     // 0..127

  float mg = -INFINITY;
#pragma unroll 16
  for (int p = 0; p < NPART; ++p)
    mg = fmaxf(mg, ws_lse[p * PSTRIDE + bkg]);

  float denom = 0.f, acc = 0.f;
#pragma unroll 8
  for (int p = 0; p < NPART; ++p) {
    const float e = __expf(ws_lse[p * PSTRIDE + bkg] - mg);
    denom += e;
    acc += e * ws_out[((size_t)p * PSTRIDE + bkg) * NDV + d];
  }
  out[(size_t)bkg * NDV + d] = acc / denom;
}

extern "C" void kernel_launch(void* const* d_in, const int* in_sizes, int n_in,
                              void* d_out, int out_size, void* d_ws, size_t ws_size,
                              hipStream_t stream) {
  const float* q        = (const float*)d_in[0];
  const float* k_cache  = (const float*)d_in[1];
  const float* v_cache  = (const float*)d_in[2];
  const int*   kv_lens  = (const int*)d_in[3];
  const int*   bt       = (const int*)d_in[4];
  float* out = (float*)d_out;

  float* ws_out = (float*)d_ws;                                  // 8.39 MB
  float* ws_lse = ws_out + (size_t)NPART * PSTRIDE * NDV;        // +64 KB

  attn_partial<<<NR * NB * NKVH * NSP, 256, 0, stream>>>(
      q, k_cache, v_cache, kv_lens, bt, ws_out, ws_lse);
  attn_combine<<<NB * NKVH * NG, NDV, 0, stream>>>(ws_out, ws_lse, out);
}